// Round 1
// 1515.038 us; speedup vs baseline: 1.1222x; 1.1222x over previous
//
#include <hip/hip_runtime.h>
#include <math.h>

#define HW 9216   // 96*96

typedef __attribute__((ext_vector_type(8))) short short8;
typedef __attribute__((ext_vector_type(4))) short short4v;
typedef __attribute__((ext_vector_type(4))) float float4v;

__device__ __forceinline__ float sigmoidf_(float x) { return 1.0f / (1.0f + expf(-x)); }

__device__ __forceinline__ short bf16rne(float f) {
  unsigned u = __builtin_bit_cast(unsigned, f);
  unsigned r = (u + 0x7FFFu + ((u >> 16) & 1u)) >> 16;
  return (short)r;
}
__device__ __forceinline__ float bf2f(short s) {
  return __builtin_bit_cast(float, ((unsigned)(unsigned short)s) << 16);
}

// ---------------------------------------------------------------------------
// Kernel W: wrap_w (192,832) fp32 -> bf16 [l][n][c]
// ---------------------------------------------------------------------------
__global__ __launch_bounds__(256) void k_wconv(const float* __restrict__ w,
                                               short* __restrict__ o)
{
  int i = blockIdx.x * 256 + threadIdx.x;
  if (i >= 192 * 832) return;
  int n = i / 832, k = i % 832;
  int l = k >> 6, c = k & 63;
  o[((size_t)l * 192 + n) * 64 + c] = bf16rne(w[i]);
}

// ---------------------------------------------------------------------------
// Kernel P: pack conv weights -> bf16 tap-GEMM layouts.
//   whK  [25][32][64]  from wh (32,64,5,5)
//   wiK  [7][32][32]   from wi (32,8,5,5)   (k32 = q*8+ch, tap = g*4+q, pad 0)
//   flK  [25][32][32]  from fl_w (26,32,5,5) (out padded 26->32 with 0)
//   i2hK [3][192][32]  from wih (192,8,3,3)  (k32 = q*8+ch, tap = g*4+q, pad 0)
// grid 400 x 256 = 102400 threads total.
// ---------------------------------------------------------------------------
__global__ __launch_bounds__(256) void k_pack(
    const float* __restrict__ wh, const float* __restrict__ wi,
    const float* __restrict__ flw, const float* __restrict__ wih,
    short* __restrict__ whK, short* __restrict__ wiK, short* __restrict__ flK,
    short* __restrict__ i2hK)
{
  int i = blockIdx.x * 256 + threadIdx.x;
  if (i < 51200) {
    int t = i / 2048, rem = i % 2048;
    int o = rem / 64, c = rem % 64;
    whK[i] = bf16rne(wh[((size_t)(o * 64 + c)) * 25 + t]);
  } else if (i < 58368) {
    int j = i - 51200;
    int g = j / 1024, rem = j % 1024;
    int o = rem / 32, k = rem % 32;
    int q = k / 8, ch = k % 8;
    int tap = g * 4 + q;
    wiK[j] = (tap < 25) ? bf16rne(wi[((size_t)(o * 8 + ch)) * 25 + tap]) : (short)0;
  } else if (i < 83968) {
    int j = i - 58368;
    int t = j / 1024, rem = j % 1024;
    int o = rem / 32, c = rem % 32;
    flK[j] = (o < 26) ? bf16rne(flw[((size_t)(o * 32 + c)) * 25 + t]) : (short)0;
  } else {
    int j = i - 83968;               // 0..18431
    int g = j / 6144, rem = j % 6144;
    int n = rem / 32, k = rem % 32;
    int q = k / 8, ch = k % 8;
    int tap = g * 4 + q;
    i2hK[j] = (tap < 9) ? bf16rne(wih[((size_t)(n * 8 + ch)) * 9 + tap]) : (short)0;
  }
}

// ---------------------------------------------------------------------------
// Kernel H: state (4,64,HW) fp32 NCHW -> hbf [b][px][64] bf16 (t=0 seed)
// ---------------------------------------------------------------------------
__global__ __launch_bounds__(256) void k_h2bf(const float* __restrict__ st,
                                              short* __restrict__ hbf)
{
  const int tid = threadIdx.x;
  const int pp = tid & 63, cg = tid >> 6;
  const int b = blockIdx.y;
  const int p = blockIdx.x * 64 + pp;
  short s[16];
  #pragma unroll
  for (int k = 0; k < 16; ++k)
    s[k] = bf16rne(st[((size_t)b * 64 + cg * 16 + k) * HW + p]);
  short* dst = hbf + ((size_t)b * HW + p) * 64 + cg * 16;
  *(short8*)dst = *(short8*)&s[0];
  *(short8*)(dst + 8) = *(short8*)&s[8];
}

// ---------------------------------------------------------------------------
// Kernel X: inputs (B,T,8,HW) fp32 -> xbf [bt][px][8] bf16. grid (36,40).
// ---------------------------------------------------------------------------
__global__ __launch_bounds__(256) void k_x2bf(const float* __restrict__ inp,
                                              short* __restrict__ xbf)
{
  const int p  = blockIdx.x * 256 + threadIdx.x;
  const int bt = blockIdx.y;
  short s[8];
  #pragma unroll
  for (int ci = 0; ci < 8; ++ci)
    s[ci] = bf16rne(inp[((size_t)bt * 8 + ci) * HW + p]);
  *(short8*)(xbf + ((size_t)bt * HW + p) * 8) = *(short8*)s;
}

// ---------------------------------------------------------------------------
// Kernel A: i2h = conv3x3(x,8->192,pad1)+bias via tap-GEMM MFMA.
// Reads xbf (bf16 ch-last), writes bf16 planar [zz][192][HW].
// M = px, N = 192 (12 tiles of 16), K = 3 groups of {tap=g*4+qd, ch 0..7}.
// block 256 = 4 waves x 32 px (two 16-px row segments, B-frags reused).
// grid (72, 40) batched / (72, 4) per-step.
// ---------------------------------------------------------------------------
__global__ __launch_bounds__(256) void k_i2h(
    const short* __restrict__ xbf, int t_off,
    const short* __restrict__ wK, const float* __restrict__ bias,
    short* __restrict__ out)
{
  const int tid  = threadIdx.x;
  const int lane = tid & 63;
  const int w    = tid >> 6;
  const int ml = lane & 15, qd = lane >> 4;
  const int zz = blockIdx.y;
  const int t = (zz >> 2) + t_off, b = zz & 3;
  const int pw0 = blockIdx.x * 128 + w * 32;
  const short* xb = xbf + ((size_t)(b * 10 + t)) * HW * 8;

  // A fragments: 2 px-segments x 3 K-groups; tap = g*4+qd, elems = 8 x-ch
  short8 afr[2][3];
  #pragma unroll
  for (int s = 0; s < 2; ++s) {
    int px0 = pw0 + s * 16;                 // 16-px segment within one row
    int y0 = px0 / 96, xc0 = px0 % 96;
    #pragma unroll
    for (int g = 0; g < 3; ++g) {
      int tap = g * 4 + qd;
      int dy = tap / 3 - 1;
      int dx = tap % 3 - 1;
      int yy = y0 + dy, xx = xc0 + ml + dx;
      bool v = (tap < 9) && (yy >= 0) && (yy < 96) && (xx >= 0) && (xx < 96);
      short8 a = {};
      if (v) a = *(const short8*)(xb + (size_t)(px0 + ml + dy * 96 + dx) * 8);
      afr[s][g] = a;
    }
  }

  float4v acc[2][12];
  #pragma unroll
  for (int s = 0; s < 2; ++s)
    #pragma unroll
    for (int j = 0; j < 12; ++j)
      #pragma unroll
      for (int r = 0; r < 4; ++r) acc[s][j][r] = 0.0f;

  #pragma unroll
  for (int j = 0; j < 12; ++j) {
    #pragma unroll
    for (int g = 0; g < 3; ++g) {
      short8 bf = *(const short8*)(wK + ((size_t)(g * 192 + j * 16 + ml)) * 32 + qd * 8);
      acc[0][j] = __builtin_amdgcn_mfma_f32_16x16x32_bf16(afr[0][g], bf, acc[0][j], 0, 0, 0);
      acc[1][j] = __builtin_amdgcn_mfma_f32_16x16x32_bf16(afr[1][g], bf, acc[1][j], 0, 0, 0);
    }
  }

  // epilogue: D row m = qd*4+r (px), col n = ml (out ch). 8B stores.
  #pragma unroll
  for (int j = 0; j < 12; ++j) {
    float bv = bias[j * 16 + ml];
    #pragma unroll
    for (int s = 0; s < 2; ++s) {
      short4v o4;
      #pragma unroll
      for (int r = 0; r < 4; ++r) o4[r] = bf16rne(acc[s][j][r] + bv);
      *(short4v*)(out + ((size_t)(zz * 192 + j * 16 + ml)) * HW
                      + pw0 + s * 16 + qd * 4) = o4;
    }
  }
}

// ---------------------------------------------------------------------------
// Kernel B: f = tanh(conv5x5(x,8->32) + conv5x5(h,64->32) + biases) via
// tap-GEMM MFMA. grid (144,4), block 256 = 4 waves x 16 px each.
// ---------------------------------------------------------------------------
__global__ __launch_bounds__(256) void k_f(
    const short* __restrict__ xbf, int t,
    const short* __restrict__ hbf,
    const short* __restrict__ whK,
    const short* __restrict__ wiK,
    const float* __restrict__ bi, const float* __restrict__ bh,
    short* __restrict__ fbf)
{
  const int tid = threadIdx.x;
  const int lane = tid & 63;
  const int w = tid >> 6;
  const int ml = lane & 15, qd = lane >> 4;
  const int b = blockIdx.y;
  const int px0 = blockIdx.x * 64 + w * 16;
  const int y0 = px0 / 96, xc0 = px0 % 96;   // 16 px are one row segment
  const int xcol = xc0 + ml;
  const int px = px0 + ml;
  const short* hb = hbf + (size_t)b * HW * 64;
  const short* xb = xbf + ((size_t)(b * 10 + t)) * HW * 8;

  float4v acc0 = {0.f, 0.f, 0.f, 0.f};
  float4v acc1 = {0.f, 0.f, 0.f, 0.f};

  // h-part: 25 taps x K=64
  #pragma unroll
  for (int ky = 0; ky < 5; ++ky) {
    int yy = y0 + ky - 2;
    if (yy < 0 || yy >= 96) continue;        // wave-uniform row skip
    #pragma unroll
    for (int kx = 0; kx < 5; ++kx) {
      int xx = xcol + kx - 2;
      bool cv = (xx >= 0) && (xx < 96);
      int off = (ky - 2) * 96 + (kx - 2);
      const short* ap = hb + (size_t)(px + off) * 64 + qd * 8;
      short8 a0 = {}, a1 = {};
      if (cv) { a0 = *(const short8*)ap; a1 = *(const short8*)(ap + 32); }
      int tap = ky * 5 + kx;
      const short* bp = whK + ((size_t)tap * 32 + ml) * 64 + qd * 8;
      short8 b00 = *(const short8*)bp;
      short8 b01 = *(const short8*)(bp + 32);
      short8 b10 = *(const short8*)(bp + 16 * 64);
      short8 b11 = *(const short8*)(bp + 16 * 64 + 32);
      acc0 = __builtin_amdgcn_mfma_f32_16x16x32_bf16(a0, b00, acc0, 0, 0, 0);
      acc0 = __builtin_amdgcn_mfma_f32_16x16x32_bf16(a1, b01, acc0, 0, 0, 0);
      acc1 = __builtin_amdgcn_mfma_f32_16x16x32_bf16(a0, b10, acc1, 0, 0, 0);
      acc1 = __builtin_amdgcn_mfma_f32_16x16x32_bf16(a1, b11, acc1, 0, 0, 0);
    }
  }

  // x-part: 7 groups of 4 taps (K slot qd -> tap g*4+qd, j -> x-channel)
  #pragma unroll
  for (int g = 0; g < 7; ++g) {
    int tap = g * 4 + qd;
    int dy = tap / 5 - 2;
    int dx = tap - (dy + 2) * 5 - 2;
    int yy = y0 + dy, xx = xcol + dx;
    bool v = (tap < 25) && (yy >= 0) && (yy < 96) && (xx >= 0) && (xx < 96);
    short8 a = {};
    if (v) a = *(const short8*)(xb + (size_t)(px + dy * 96 + dx) * 8);
    const short* bp = wiK + ((size_t)g * 32 + ml) * 32 + qd * 8;
    short8 b0 = *(const short8*)bp;
    short8 b1 = *(const short8*)(bp + 16 * 32);
    acc0 = __builtin_amdgcn_mfma_f32_16x16x32_bf16(a, b0, acc0, 0, 0, 0);
    acc1 = __builtin_amdgcn_mfma_f32_16x16x32_bf16(a, b1, acc1, 0, 0, 0);
  }

  // epilogue: D row m=qd*4+r (px), col n=ml (out)
  short* fo = fbf + (size_t)b * HW * 32;
  #pragma unroll
  for (int i = 0; i < 2; ++i) {
    int o = i * 16 + ml;
    float bias = bi[o] + bh[o];
    float4v a = i ? acc1 : acc0;
    #pragma unroll
    for (int r = 0; r < 4; ++r) {
      int p2 = px0 + qd * 4 + r;
      fo[(size_t)p2 * 32 + o] = bf16rne(tanhf(a[r] + bias));
    }
  }
}

// ---------------------------------------------------------------------------
// Kernel C: flows = conv5x5(f, 32->26) + bias via tap-GEMM MFMA.
// grid (144,4), block 256. Writes planar fp32 (B,26,HW).
// ---------------------------------------------------------------------------
__global__ __launch_bounds__(256) void k_flows(
    const short* __restrict__ fbf,
    const short* __restrict__ flK,
    const float* __restrict__ bias,
    float* __restrict__ fls)
{
  const int tid = threadIdx.x;
  const int lane = tid & 63;
  const int w = tid >> 6;
  const int ml = lane & 15, qd = lane >> 4;
  const int b = blockIdx.y;
  const int px0 = blockIdx.x * 64 + w * 16;
  const int y0 = px0 / 96, xc0 = px0 % 96;
  const int xcol = xc0 + ml;
  const int px = px0 + ml;
  const short* fb = fbf + (size_t)b * HW * 32;

  float4v acc0 = {0.f, 0.f, 0.f, 0.f};
  float4v acc1 = {0.f, 0.f, 0.f, 0.f};

  #pragma unroll
  for (int ky = 0; ky < 5; ++ky) {
    int yy = y0 + ky - 2;
    if (yy < 0 || yy >= 96) continue;
    #pragma unroll
    for (int kx = 0; kx < 5; ++kx) {
      int xx = xcol + kx - 2;
      bool cv = (xx >= 0) && (xx < 96);
      int off = (ky - 2) * 96 + (kx - 2);
      short8 a = {};
      if (cv) a = *(const short8*)(fb + (size_t)(px + off) * 32 + qd * 8);
      int tap = ky * 5 + kx;
      const short* bp = flK + ((size_t)tap * 32 + ml) * 32 + qd * 8;
      short8 b0 = *(const short8*)bp;
      short8 b1 = *(const short8*)(bp + 16 * 32);
      acc0 = __builtin_amdgcn_mfma_f32_16x16x32_bf16(a, b0, acc0, 0, 0, 0);
      acc1 = __builtin_amdgcn_mfma_f32_16x16x32_bf16(a, b1, acc1, 0, 0, 0);
    }
  }

  float* fo = fls + (size_t)b * 26 * HW;
  #pragma unroll
  for (int i = 0; i < 2; ++i) {
    int o = i * 16 + ml;
    if (o < 26) {
      float bv = bias[o];
      float4v a = i ? acc1 : acc0;
      #pragma unroll
      for (int r = 0; r < 4; ++r)
        fo[(size_t)o * HW + px0 + qd * 4 + r] = a[r] + bv;
    }
  }
}

// ---------------------------------------------------------------------------
// Kernel D: fused warp (channel-last bf16 h) + 1x1 conv (bf16 MFMA) + gates.
// 1-D grid 576, XCD-batch affinity swizzle. i2h read as bf16.
// ---------------------------------------------------------------------------
__global__ __launch_bounds__(256) void k_fused(
    const float* __restrict__ fls,
    const float* __restrict__ hbase, long long hstr,
    const short* __restrict__ hbf_in,
    const short* __restrict__ i2h,                // bf16 [4][192][HW] (this step)
    const short* __restrict__ wbf,
    const float* __restrict__ wb,
    float* __restrict__ outb, long long ostr,
    short* __restrict__ hbf_out,
    float* __restrict__ lastb)
{
  __shared__ __align__(16) char smem_raw[49920];
  short* lds_w = (short*)smem_raw;
  short* lds_v = lds_w + 192 * 72;
  float* lds_h = (float*)smem_raw;
  short* hpack = (short*)smem_raw;

  const int tid = threadIdx.x;
  const int pp  = tid & 63;
  const int cg  = tid >> 6;
  const int ii  = blockIdx.x;
  const int xcd = ii & 7;
  const int b   = xcd >> 1;
  const int tile = ((ii >> 3) << 1) | (xcd & 1);
  const int p   = tile * 64 + pp;
  const int ypix = p / 96, xpix = p % 96;
  const float* hb  = hbase + (size_t)b * hstr;
  const short* hvp = hbf_in + ((size_t)b * HW) * 64 + cg * 16;
  const float* flb = fls + (size_t)b * 26 * HW;
  const int ml = pp & 15;
  const int qd = pp >> 4;

  float4v acc[3][4];
  #pragma unroll
  for (int i = 0; i < 3; ++i)
    #pragma unroll
    for (int j = 0; j < 4; ++j)
      #pragma unroll
      for (int r = 0; r < 4; ++r) acc[i][j][r] = 0.0f;

  for (int l = 0; l < 13; ++l) {
    __syncthreads();
    {
      const short* wsrc = wbf + (size_t)l * 192 * 64;
      #pragma unroll
      for (int it = 0; it < 6; ++it) {
        int idx = tid + it * 256;
        int n = idx >> 3, c8 = (idx & 7) * 8;
        short8 v = *(const short8*)(wsrc + n * 64 + c8);
        *(short8*)(lds_w + n * 72 + c8) = v;
      }
    }
    float fx = flb[(size_t)(2 * l) * HW + p];
    float fy = flb[(size_t)(2 * l + 1) * HW + p];
    float vx = (float)xpix - fx;
    float vy = (float)ypix - fy;
    float gxn = 2.0f * vx / 96.0f - 1.0f;
    float gyn = 2.0f * vy / 96.0f - 1.0f;
    float ix = ((gxn + 1.0f) * 96.0f - 1.0f) * 0.5f;
    float iy = ((gyn + 1.0f) * 96.0f - 1.0f) * 0.5f;
    float x0f = floorf(ix), y0f = floorf(iy);
    float wx1 = ix - x0f, wy1 = iy - y0f;
    float wx0 = 1.0f - wx1, wy0 = 1.0f - wy1;
    int x0 = (int)x0f, y0 = (int)y0f;
    bool vx0 = (x0 >= 0) && (x0 < 96);
    bool vx1 = (x0 + 1 >= 0) && (x0 + 1 < 96);
    bool vy0g = (y0 >= 0) && (y0 < 96);
    bool vy1g = (y0 + 1 >= 0) && (y0 + 1 < 96);
    int o00 = (vx0 && vy0g) ? (y0 * 96 + x0)           : -1;
    int o01 = (vx1 && vy0g) ? (y0 * 96 + x0 + 1)       : -1;
    int o10 = (vx0 && vy1g) ? ((y0 + 1) * 96 + x0)     : -1;
    int o11 = (vx1 && vy1g) ? ((y0 + 1) * 96 + x0 + 1) : -1;
    float w00 = wy0 * wx0, w01 = wy0 * wx1, w10 = wy1 * wx0, w11 = wy1 * wx1;

    float sum[16];
    #pragma unroll
    for (int k = 0; k < 16; ++k) sum[k] = 0.0f;
    #define TAP_(off, wgt)                                            \
      if ((off) >= 0) {                                               \
        const short* tp = hvp + (size_t)(off) * 64;                   \
        short8 u0 = *(const short8*)tp;                               \
        short8 u1 = *(const short8*)(tp + 8);                         \
        _Pragma("unroll")                                             \
        for (int k = 0; k < 8; ++k) {                                 \
          sum[k]     += (wgt) * bf2f(u0[k]);                          \
          sum[k + 8] += (wgt) * bf2f(u1[k]);                          \
        }                                                             \
      }
    TAP_(o00, w00) TAP_(o01, w01) TAP_(o10, w10) TAP_(o11, w11)
    #undef TAP_
    short vv[16];
    #pragma unroll
    for (int k = 0; k < 16; ++k) vv[k] = bf16rne(sum[k]);
    *(short8*)(lds_v + pp * 72 + cg * 16)     = *(short8*)&vv[0];
    *(short8*)(lds_v + pp * 72 + cg * 16 + 8) = *(short8*)&vv[8];
    __syncthreads();

    #pragma unroll
    for (int ks = 0; ks < 2; ++ks) {
      short8 af[3], bfr[4];
      #pragma unroll
      for (int i = 0; i < 3; ++i)
        af[i] = *(const short8*)(lds_w + (48 * cg + i * 16 + ml) * 72 + ks * 32 + qd * 8);
      #pragma unroll
      for (int j = 0; j < 4; ++j)
        bfr[j] = *(const short8*)(lds_v + (j * 16 + ml) * 72 + ks * 32 + qd * 8);
      #pragma unroll
      for (int i = 0; i < 3; ++i)
        #pragma unroll
        for (int j = 0; j < 4; ++j)
          acc[i][j] = __builtin_amdgcn_mfma_f32_16x16x32_bf16(af[i], bfr[j], acc[i][j], 0, 0, 0);
    }
  }

  __syncthreads();
  #pragma unroll
  for (int i = 0; i < 3; ++i)
    #pragma unroll
    for (int j = 0; j < 4; ++j)
      #pragma unroll
      for (int r = 0; r < 4; ++r) {
        int ch = 48 * cg + i * 16 + qd * 4 + r;
        int px = j * 16 + ml;
        lds_h[ch * 65 + px] = acc[i][j][r];
      }
  __syncthreads();

  const short* i2hb = i2h + (size_t)b * 192 * HW + p;
  float* ob = outb + (size_t)b * ostr;
  float hnv[16];
  #pragma unroll
  for (int k = 0; k < 16; ++k) {
    int cch = cg + k * 4;
    float rh = lds_h[cch * 65 + pp] + wb[cch];
    float uh = lds_h[(64 + cch) * 65 + pp] + wb[64 + cch];
    float nh = lds_h[(128 + cch) * 65 + pp] + wb[128 + cch];
    float rt = bf2f(i2hb[(size_t)cch * HW]);
    float ut = bf2f(i2hb[(size_t)(64 + cch) * HW]);
    float nt = bf2f(i2hb[(size_t)(128 + cch) * HW]);
    float rr = sigmoidf_(rt + rh);
    float uu = sigmoidf_(ut + uh);
    float nn = sigmoidf_(nt + rr * nh);
    float hp = hb[(size_t)cch * HW + p];
    float hn = (1.0f - uu) * nn + uu * hp;
    ob[(size_t)cch * HW + p] = hn;
    if (lastb) lastb[((size_t)b * 64 + cch) * HW + p] = hn;
    hnv[k] = hn;
  }

  __syncthreads();
  #pragma unroll
  for (int k = 0; k < 16; ++k)
    hpack[pp * 80 + cg + 4 * k] = bf16rne(hnv[k]);
  __syncthreads();
  {
    int px = tid >> 2, g = tid & 3;
    short8 a0 = *(short8*)(hpack + px * 80 + g * 16);
    short8 a1 = *(short8*)(hpack + px * 80 + g * 16 + 8);
    short* dst = hbf_out + ((size_t)b * HW + tile * 64 + px) * 64 + g * 16;
    *(short8*)dst = a0;
    *(short8*)(dst + 8) = a1;
  }
}

// ---------------------------------------------------------------------------
extern "C" void kernel_launch(void* const* d_in, const int* in_sizes, int n_in,
                              void* d_out, int out_size, void* d_ws, size_t ws_size,
                              hipStream_t stream)
{
  const float* inp   = (const float*)d_in[0];
  const float* state = (const float*)d_in[1];
  const float* i2h_w = (const float*)d_in[2];
  const float* i2h_b = (const float*)d_in[3];
  const float* i2f_w = (const float*)d_in[4];
  const float* i2f_b = (const float*)d_in[5];
  const float* h2f_w = (const float*)d_in[6];
  const float* h2f_b = (const float*)d_in[7];
  const float* fl_w  = (const float*)d_in[8];
  const float* fl_b  = (const float*)d_in[9];
  const float* wr_w  = (const float*)d_in[10];
  const float* wr_b  = (const float*)d_in[11];
  float* out = (float*)d_out;
  float* ws  = (float*)d_ws;

  // sizes in floats
  const long long F_I2HB1 = 3538944;   // one step: 4*192*HW shorts /2
  const long long F_FBF   = 589824;    // 4*HW*32 shorts /2
  const long long F_FLS   = 958464;    // 4*26*HW fp32
  const long long F_HB    = 1179648;   // 4*HW*64 shorts /2
  const long long F_XBF   = 1474560;   // 40*HW*8 shorts /2
  const long long F_WBF   = 79872;
  const long long F_WHK   = 25600;
  const long long F_WIK   = 3584;
  const long long F_FLK   = 12800;
  const long long F_I2HK  = 9216;      // 3*192*32 shorts /2
  const long long OB      = (long long)10 * 64 * HW;

  const long long fixed = F_FBF + F_FLS + 2 * F_HB + F_XBF + F_WBF
                        + F_WHK + F_WIK + F_FLK + F_I2HK;
  bool batched = ws_size >= (size_t)(10 * F_I2HB1 + fixed) * 4ULL;
  long long i2h_fl = batched ? 10 * F_I2HB1 : F_I2HB1;

  short* ws_i2h = (short*)ws;
  float* fwp    = ws + i2h_fl;
  float* ws_fbf_f = fwp;              fwp += F_FBF;
  float* ws_fls   = fwp;              fwp += F_FLS;
  float* hbfA_f   = fwp;              fwp += F_HB;
  float* hbfB_f   = fwp;              fwp += F_HB;
  float* xbf_f    = fwp;              fwp += F_XBF;
  float* wbf_f    = fwp;              fwp += F_WBF;
  float* whK_f    = fwp;              fwp += F_WHK;
  float* wiK_f    = fwp;              fwp += F_WIK;
  float* flK_f    = fwp;              fwp += F_FLK;
  float* i2hK_f   = fwp;
  short* ws_fbf  = (short*)ws_fbf_f;
  short* hbfA    = (short*)hbfA_f;
  short* hbfB    = (short*)hbfB_f;
  short* ws_xbf  = (short*)xbf_f;
  short* ws_wbf  = (short*)wbf_f;
  short* ws_whK  = (short*)whK_f;
  short* ws_wiK  = (short*)wiK_f;
  short* ws_flK  = (short*)flK_f;
  short* ws_i2hK = (short*)i2hK_f;

  k_wconv<<<dim3(624), 256, 0, stream>>>(wr_w, ws_wbf);
  k_pack<<<dim3(400), 256, 0, stream>>>(h2f_w, i2f_w, fl_w, i2h_w,
                                        ws_whK, ws_wiK, ws_flK, ws_i2hK);
  k_h2bf<<<dim3(144, 4), 256, 0, stream>>>(state, hbfA);
  k_x2bf<<<dim3(36, 40), 256, 0, stream>>>(inp, ws_xbf);
  if (batched)
    k_i2h<<<dim3(72, 40), 256, 0, stream>>>(ws_xbf, 0, ws_i2hK, i2h_b, ws_i2h);

  for (int t = 0; t < 10; ++t) {
    const float* hbase = (t == 0) ? state : (out + (size_t)(t - 1) * 64 * HW);
    long long hstr = (t == 0) ? (long long)64 * HW : OB;
    short* hin  = (t & 1) ? hbfB : hbfA;
    short* hout = (t & 1) ? hbfA : hbfB;

    if (!batched)
      k_i2h<<<dim3(72, 4), 256, 0, stream>>>(ws_xbf, t, ws_i2hK, i2h_b, ws_i2h);
    k_f<<<dim3(144, 4), 256, 0, stream>>>(ws_xbf, t, hin, ws_whK, ws_wiK,
                                          i2f_b, h2f_b, ws_fbf);
    k_flows<<<dim3(144, 4), 256, 0, stream>>>(ws_fbf, ws_flK, fl_b, ws_fls);

    const short* i2h_t = batched ? (ws_i2h + (size_t)t * 2 * F_I2HB1) : ws_i2h;
    float* outbase = out + (size_t)t * 64 * HW;
    float* lastb = (t == 9) ? (out + (size_t)4 * 10 * 64 * HW) : nullptr;
    k_fused<<<dim3(576), 256, 0, stream>>>(ws_fls, hbase, hstr, hin, i2h_t,
                                           ws_wbf, wr_b, outbase, OB, hout, lastb);
  }
}

// Round 3
// 1494.838 us; speedup vs baseline: 1.1373x; 1.0135x over previous
//
#include <hip/hip_runtime.h>
#include <math.h>

#define HW 9216   // 96*96

typedef __attribute__((ext_vector_type(8))) short short8;
typedef __attribute__((ext_vector_type(4))) short short4v;
typedef __attribute__((ext_vector_type(4))) float float4v;

__device__ __forceinline__ float sigmoidf_(float x) { return 1.0f / (1.0f + expf(-x)); }

__device__ __forceinline__ short bf16rne(float f) {
  unsigned u = __builtin_bit_cast(unsigned, f);
  unsigned r = (u + 0x7FFFu + ((u >> 16) & 1u)) >> 16;
  return (short)r;
}
__device__ __forceinline__ float bf2f(short s) {
  return __builtin_bit_cast(float, ((unsigned)(unsigned short)s) << 16);
}

// ---------------------------------------------------------------------------
// Kernel W: wrap_w (192,832) fp32 -> bf16 [l][n][c]
// ---------------------------------------------------------------------------
__global__ __launch_bounds__(256) void k_wconv(const float* __restrict__ w,
                                               short* __restrict__ o)
{
  int i = blockIdx.x * 256 + threadIdx.x;
  if (i >= 192 * 832) return;
  int n = i / 832, k = i % 832;
  int l = k >> 6, c = k & 63;
  o[((size_t)l * 192 + n) * 64 + c] = bf16rne(w[i]);
}

// ---------------------------------------------------------------------------
// Kernel P: pack conv weights -> bf16 tap-GEMM layouts.
//   whK  [25][32][64]  from wh (32,64,5,5)
//   wiK  [7][32][32]   from wi (32,8,5,5)   (k32 = q*8+ch, tap = g*4+q, pad 0)
//   flK  [25][32][32]  from fl_w (26,32,5,5) (out padded 26->32 with 0)
//   i2hK [3][192][32]  from wih (192,8,3,3)  (k32 = q*8+ch, tap = g*4+q, pad 0)
// ---------------------------------------------------------------------------
__global__ __launch_bounds__(256) void k_pack(
    const float* __restrict__ wh, const float* __restrict__ wi,
    const float* __restrict__ flw, const float* __restrict__ wih,
    short* __restrict__ whK, short* __restrict__ wiK, short* __restrict__ flK,
    short* __restrict__ i2hK)
{
  int i = blockIdx.x * 256 + threadIdx.x;
  if (i < 51200) {
    int t = i / 2048, rem = i % 2048;
    int o = rem / 64, c = rem % 64;
    whK[i] = bf16rne(wh[((size_t)(o * 64 + c)) * 25 + t]);
  } else if (i < 58368) {
    int j = i - 51200;
    int g = j / 1024, rem = j % 1024;
    int o = rem / 32, k = rem % 32;
    int q = k / 8, ch = k % 8;
    int tap = g * 4 + q;
    wiK[j] = (tap < 25) ? bf16rne(wi[((size_t)(o * 8 + ch)) * 25 + tap]) : (short)0;
  } else if (i < 83968) {
    int j = i - 58368;
    int t = j / 1024, rem = j % 1024;
    int o = rem / 32, c = rem % 32;
    flK[j] = (o < 26) ? bf16rne(flw[((size_t)(o * 32 + c)) * 25 + t]) : (short)0;
  } else {
    int j = i - 83968;               // 0..18431
    int g = j / 6144, rem = j % 6144;
    int n = rem / 32, k = rem % 32;
    int q = k / 8, ch = k % 8;
    int tap = g * 4 + q;
    i2hK[j] = (tap < 9) ? bf16rne(wih[((size_t)(n * 8 + ch)) * 9 + tap]) : (short)0;
  }
}

// ---------------------------------------------------------------------------
// Kernel H: state (4,64,HW) fp32 NCHW -> hbf [b][px][64] bf16 (t=0 seed)
// ---------------------------------------------------------------------------
__global__ __launch_bounds__(256) void k_h2bf(const float* __restrict__ st,
                                              short* __restrict__ hbf)
{
  const int tid = threadIdx.x;
  const int pp = tid & 63, cg = tid >> 6;
  const int b = blockIdx.y;
  const int p = blockIdx.x * 64 + pp;
  short s[16];
  #pragma unroll
  for (int k = 0; k < 16; ++k)
    s[k] = bf16rne(st[((size_t)b * 64 + cg * 16 + k) * HW + p]);
  short* dst = hbf + ((size_t)b * HW + p) * 64 + cg * 16;
  *(short8*)dst = *(short8*)&s[0];
  *(short8*)(dst + 8) = *(short8*)&s[8];
}

// ---------------------------------------------------------------------------
// Kernel X: inputs (B,T,8,HW) fp32 -> xbf [bt][px][8] bf16. grid (36,40).
// ---------------------------------------------------------------------------
__global__ __launch_bounds__(256) void k_x2bf(const float* __restrict__ inp,
                                              short* __restrict__ xbf)
{
  const int p  = blockIdx.x * 256 + threadIdx.x;
  const int bt = blockIdx.y;
  short s[8];
  #pragma unroll
  for (int ci = 0; ci < 8; ++ci)
    s[ci] = bf16rne(inp[((size_t)bt * 8 + ci) * HW + p]);
  *(short8*)(xbf + ((size_t)bt * HW + p) * 8) = *(short8*)s;
}

// ---------------------------------------------------------------------------
// Kernel A: i2h = conv3x3(x,8->192,pad1)+bias via tap-GEMM MFMA.
// Reads xbf (bf16 ch-last), writes bf16 planar [zz][192][HW].
// Epilogue bounces through LDS [192][136] so global stores are 256B runs.
// grid (72, 40) batched / (72, 4) per-step.
// ---------------------------------------------------------------------------
__global__ __launch_bounds__(256) void k_i2h(
    const short* __restrict__ xbf, int t_off,
    const short* __restrict__ wK, const float* __restrict__ bias,
    short* __restrict__ out)
{
  __shared__ __align__(16) short lds_o[192 * 136];
  const int tid  = threadIdx.x;
  const int lane = tid & 63;
  const int w    = tid >> 6;
  const int ml = lane & 15, qd = lane >> 4;
  const int zz = blockIdx.y;
  const int t = (zz >> 2) + t_off, b = zz & 3;
  const int pw0 = blockIdx.x * 128 + w * 32;
  const short* xb = xbf + ((size_t)(b * 10 + t)) * HW * 8;

  // A fragments: 2 px-segments x 3 K-groups; tap = g*4+qd, elems = 8 x-ch
  short8 afr[2][3];
  #pragma unroll
  for (int s = 0; s < 2; ++s) {
    int px0 = pw0 + s * 16;                 // 16-px segment within one row
    int y0 = px0 / 96, xc0 = px0 % 96;
    #pragma unroll
    for (int g = 0; g < 3; ++g) {
      int tap = g * 4 + qd;
      int dy = tap / 3 - 1;
      int dx = tap % 3 - 1;
      int yy = y0 + dy, xx = xc0 + ml + dx;
      bool v = (tap < 9) && (yy >= 0) && (yy < 96) && (xx >= 0) && (xx < 96);
      short8 a = {};
      if (v) a = *(const short8*)(xb + (size_t)(px0 + ml + dy * 96 + dx) * 8);
      afr[s][g] = a;
    }
  }

  float4v acc[2][12];
  #pragma unroll
  for (int s = 0; s < 2; ++s)
    #pragma unroll
    for (int j = 0; j < 12; ++j)
      #pragma unroll
      for (int r = 0; r < 4; ++r) acc[s][j][r] = 0.0f;

  #pragma unroll
  for (int j = 0; j < 12; ++j) {
    #pragma unroll
    for (int g = 0; g < 3; ++g) {
      short8 bf = *(const short8*)(wK + ((size_t)(g * 192 + j * 16 + ml)) * 32 + qd * 8);
      acc[0][j] = __builtin_amdgcn_mfma_f32_16x16x32_bf16(afr[0][g], bf, acc[0][j], 0, 0, 0);
      acc[1][j] = __builtin_amdgcn_mfma_f32_16x16x32_bf16(afr[1][g], bf, acc[1][j], 0, 0, 0);
    }
  }

  // epilogue: D row m = qd*4+r (px), col n = ml (out ch) -> LDS [ch][136]
  #pragma unroll
  for (int j = 0; j < 12; ++j) {
    float bv = bias[j * 16 + ml];
    #pragma unroll
    for (int s = 0; s < 2; ++s) {
      short4v o4;
      #pragma unroll
      for (int r = 0; r < 4; ++r) o4[r] = bf16rne(acc[s][j][r] + bv);
      *(short4v*)(lds_o + (j * 16 + ml) * 136 + w * 32 + s * 16 + qd * 4) = o4;
    }
  }
  __syncthreads();
  // coalesced writeout: 12 iters x (16 rows x 16 lanes x 16B).
  // covers all 192 rows x 128 px; each row segment = 256B contiguous.
  const int pblk = blockIdx.x * 128;
  #pragma unroll
  for (int k = 0; k < 12; ++k) {
    int r = (tid >> 4) + k * 16;
    short8 vvv = *(short8*)(lds_o + r * 136 + (tid & 15) * 8);
    *(short8*)(out + ((size_t)(zz * 192 + r)) * HW + pblk + (tid & 15) * 8) = vvv;
  }
}

// ---------------------------------------------------------------------------
// Kernel B: f = tanh(conv5x5(x,8->32) + conv5x5(h,64->32) + biases) via
// tap-GEMM MFMA. grid (144,4), block 256 = 4 waves x 16 px each.
// ---------------------------------------------------------------------------
__global__ __launch_bounds__(256) void k_f(
    const short* __restrict__ xbf, int t,
    const short* __restrict__ hbf,
    const short* __restrict__ whK,
    const short* __restrict__ wiK,
    const float* __restrict__ bi, const float* __restrict__ bh,
    short* __restrict__ fbf)
{
  const int tid = threadIdx.x;
  const int lane = tid & 63;
  const int w = tid >> 6;
  const int ml = lane & 15, qd = lane >> 4;
  const int b = blockIdx.y;
  const int px0 = blockIdx.x * 64 + w * 16;
  const int y0 = px0 / 96, xc0 = px0 % 96;   // 16 px are one row segment
  const int xcol = xc0 + ml;
  const int px = px0 + ml;
  const short* hb = hbf + (size_t)b * HW * 64;
  const short* xb = xbf + ((size_t)(b * 10 + t)) * HW * 8;

  float4v acc0 = {0.f, 0.f, 0.f, 0.f};
  float4v acc1 = {0.f, 0.f, 0.f, 0.f};

  // h-part: 25 taps x K=64
  #pragma unroll
  for (int ky = 0; ky < 5; ++ky) {
    int yy = y0 + ky - 2;
    if (yy < 0 || yy >= 96) continue;        // wave-uniform row skip
    #pragma unroll
    for (int kx = 0; kx < 5; ++kx) {
      int xx = xcol + kx - 2;
      bool cv = (xx >= 0) && (xx < 96);
      int off = (ky - 2) * 96 + (kx - 2);
      const short* ap = hb + (size_t)(px + off) * 64 + qd * 8;
      short8 a0 = {}, a1 = {};
      if (cv) { a0 = *(const short8*)ap; a1 = *(const short8*)(ap + 32); }
      int tap = ky * 5 + kx;
      const short* bp = whK + ((size_t)tap * 32 + ml) * 64 + qd * 8;
      short8 b00 = *(const short8*)bp;
      short8 b01 = *(const short8*)(bp + 32);
      short8 b10 = *(const short8*)(bp + 16 * 64);
      short8 b11 = *(const short8*)(bp + 16 * 64 + 32);
      acc0 = __builtin_amdgcn_mfma_f32_16x16x32_bf16(a0, b00, acc0, 0, 0, 0);
      acc0 = __builtin_amdgcn_mfma_f32_16x16x32_bf16(a1, b01, acc0, 0, 0, 0);
      acc1 = __builtin_amdgcn_mfma_f32_16x16x32_bf16(a0, b10, acc1, 0, 0, 0);
      acc1 = __builtin_amdgcn_mfma_f32_16x16x32_bf16(a1, b11, acc1, 0, 0, 0);
    }
  }

  // x-part: 7 groups of 4 taps (K slot qd -> tap g*4+qd, j -> x-channel)
  #pragma unroll
  for (int g = 0; g < 7; ++g) {
    int tap = g * 4 + qd;
    int dy = tap / 5 - 2;
    int dx = tap - (dy + 2) * 5 - 2;
    int yy = y0 + dy, xx = xcol + dx;
    bool v = (tap < 25) && (yy >= 0) && (yy < 96) && (xx >= 0) && (xx < 96);
    short8 a = {};
    if (v) a = *(const short8*)(xb + (size_t)(px + dy * 96 + dx) * 8);
    const short* bp = wiK + ((size_t)g * 32 + ml) * 32 + qd * 8;
    short8 b0 = *(const short8*)bp;
    short8 b1 = *(const short8*)(bp + 16 * 32);
    acc0 = __builtin_amdgcn_mfma_f32_16x16x32_bf16(a, b0, acc0, 0, 0, 0);
    acc1 = __builtin_amdgcn_mfma_f32_16x16x32_bf16(a, b1, acc1, 0, 0, 0);
  }

  // epilogue: D row m=qd*4+r (px), col n=ml (out)
  short* fo = fbf + (size_t)b * HW * 32;
  #pragma unroll
  for (int i = 0; i < 2; ++i) {
    int o = i * 16 + ml;
    float bias = bi[o] + bh[o];
    float4v a = i ? acc1 : acc0;
    #pragma unroll
    for (int r = 0; r < 4; ++r) {
      int p2 = px0 + qd * 4 + r;
      fo[(size_t)p2 * 32 + o] = bf16rne(tanhf(a[r] + bias));
    }
  }
}

// ---------------------------------------------------------------------------
// Kernel C: flows = conv5x5(f, 32->26) + bias via tap-GEMM MFMA.
// grid (144,4), block 256. Writes planar fp32 (B,26,HW).
// ---------------------------------------------------------------------------
__global__ __launch_bounds__(256) void k_flows(
    const short* __restrict__ fbf,
    const short* __restrict__ flK,
    const float* __restrict__ bias,
    float* __restrict__ fls)
{
  const int tid = threadIdx.x;
  const int lane = tid & 63;
  const int w = tid >> 6;
  const int ml = lane & 15, qd = lane >> 4;
  const int b = blockIdx.y;
  const int px0 = blockIdx.x * 64 + w * 16;
  const int y0 = px0 / 96, xc0 = px0 % 96;
  const int xcol = xc0 + ml;
  const int px = px0 + ml;
  const short* fb = fbf + (size_t)b * HW * 32;

  float4v acc0 = {0.f, 0.f, 0.f, 0.f};
  float4v acc1 = {0.f, 0.f, 0.f, 0.f};

  #pragma unroll
  for (int ky = 0; ky < 5; ++ky) {
    int yy = y0 + ky - 2;
    if (yy < 0 || yy >= 96) continue;
    #pragma unroll
    for (int kx = 0; kx < 5; ++kx) {
      int xx = xcol + kx - 2;
      bool cv = (xx >= 0) && (xx < 96);
      int off = (ky - 2) * 96 + (kx - 2);
      short8 a = {};
      if (cv) a = *(const short8*)(fb + (size_t)(px + off) * 32 + qd * 8);
      int tap = ky * 5 + kx;
      const short* bp = flK + ((size_t)tap * 32 + ml) * 32 + qd * 8;
      short8 b0 = *(const short8*)bp;
      short8 b1 = *(const short8*)(bp + 16 * 32);
      acc0 = __builtin_amdgcn_mfma_f32_16x16x32_bf16(a, b0, acc0, 0, 0, 0);
      acc1 = __builtin_amdgcn_mfma_f32_16x16x32_bf16(a, b1, acc1, 0, 0, 0);
    }
  }

  float* fo = fls + (size_t)b * 26 * HW;
  #pragma unroll
  for (int i = 0; i < 2; ++i) {
    int o = i * 16 + ml;
    if (o < 26) {
      float bv = bias[o];
      float4v a = i ? acc1 : acc0;
      #pragma unroll
      for (int r = 0; r < 4; ++r)
        fo[(size_t)o * HW + px0 + qd * 4 + r] = a[r] + bv;
    }
  }
}

// ---------------------------------------------------------------------------
// Kernel D: fused warp + 1x1 conv + gates, SOFTWARE-PIPELINED L-loop.
// Per iter: syncA -> commit wreg/vv(l) to LDS -> syncB ->
//           issue weight+gather loads(l+1) -> MFMA(l) || pack vv(l+1).
// All global latency hides under the MFMA window. Flows preloaded to LDS.
// ---------------------------------------------------------------------------
__global__ __launch_bounds__(256, 3) void k_fused(
    const float* __restrict__ fls,
    const float* __restrict__ hbase, long long hstr,
    const short* __restrict__ hbf_in,
    const short* __restrict__ i2h,                // bf16 [4][192][HW] (this step)
    const short* __restrict__ wbf,
    const float* __restrict__ wb,
    float* __restrict__ outb, long long ostr,
    short* __restrict__ hbf_out,
    float* __restrict__ lastb)
{
  __shared__ __align__(16) char smem_raw[49920];
  short* lds_w = (short*)smem_raw;              // 192*72 shorts = 27648 B
  short* lds_v = lds_w + 192 * 72;              // 64*72 shorts  =  9216 B
  float* lds_f = (float*)(smem_raw + 36864);    // 64*26 floats  =  6656 B
  float* lds_h = (float*)smem_raw;              // epilogue (union)
  short* hpack = (short*)smem_raw;

  const int tid = threadIdx.x;
  const int pp  = tid & 63;
  const int cg  = tid >> 6;
  const int ii  = blockIdx.x;
  const int xcd = ii & 7;
  const int b   = xcd >> 1;
  const int tile = ((ii >> 3) << 1) | (xcd & 1);
  const int p   = tile * 64 + pp;
  const int ypix = p / 96, xpix = p % 96;
  const float* hb  = hbase + (size_t)b * hstr;
  const short* hvp = hbf_in + ((size_t)b * HW) * 64 + cg * 16;
  const float* flb = fls + (size_t)b * 26 * HW;
  const int ml = pp & 15;
  const int qd = pp >> 4;

  // preload all 26 flow planes for this tile into LDS [pp][26]
  #pragma unroll
  for (int it = 0; it < 7; ++it) {
    int idx = it * 256 + tid;
    if (idx < 1664) {
      int c = idx >> 6, pp2 = idx & 63;
      lds_f[pp2 * 26 + c] = flb[(size_t)c * HW + tile * 64 + pp2];
    }
  }

  float4v acc[3][4];
  #pragma unroll
  for (int i = 0; i < 3; ++i)
    #pragma unroll
    for (int j = 0; j < 4; ++j)
      #pragma unroll
      for (int r = 0; r < 4; ++r) acc[i][j][r] = 0.0f;

  int   o_[4];
  float wt_[4];
  short8 u_[4][2];
  short8 wreg[6];
  short vv[16];

  auto comp_offs = [&](int l) {
    float fx = lds_f[pp * 26 + 2 * l];
    float fy = lds_f[pp * 26 + 2 * l + 1];
    float vx = (float)xpix - fx;
    float vy = (float)ypix - fy;
    float gxn = 2.0f * vx / 96.0f - 1.0f;
    float gyn = 2.0f * vy / 96.0f - 1.0f;
    float ix = ((gxn + 1.0f) * 96.0f - 1.0f) * 0.5f;
    float iy = ((gyn + 1.0f) * 96.0f - 1.0f) * 0.5f;
    float x0f = floorf(ix), y0f = floorf(iy);
    float wx1 = ix - x0f, wy1 = iy - y0f;
    float wx0 = 1.0f - wx1, wy0 = 1.0f - wy1;
    int x0 = (int)x0f, y0 = (int)y0f;
    bool vx0 = (x0 >= 0) && (x0 < 96);
    bool vx1 = (x0 + 1 >= 0) && (x0 + 1 < 96);
    bool vy0g = (y0 >= 0) && (y0 < 96);
    bool vy1g = (y0 + 1 >= 0) && (y0 + 1 < 96);
    o_[0] = (vx0 && vy0g) ? (y0 * 96 + x0)           : -1;
    o_[1] = (vx1 && vy0g) ? (y0 * 96 + x0 + 1)       : -1;
    o_[2] = (vx0 && vy1g) ? ((y0 + 1) * 96 + x0)     : -1;
    o_[3] = (vx1 && vy1g) ? ((y0 + 1) * 96 + x0 + 1) : -1;
    wt_[0] = wy0 * wx0; wt_[1] = wy0 * wx1; wt_[2] = wy1 * wx0; wt_[3] = wy1 * wx1;
  };
  auto load_gather = [&]() {
    #pragma unroll
    for (int q = 0; q < 4; ++q) {
      short8 z = {};
      u_[q][0] = z; u_[q][1] = z;
      if (o_[q] >= 0) {
        const short* tp = hvp + (size_t)o_[q] * 64;
        u_[q][0] = *(const short8*)tp;
        u_[q][1] = *(const short8*)(tp + 8);
      }
    }
  };
  auto load_w = [&](int l) {
    const short* wsrc = wbf + (size_t)l * 192 * 64;
    #pragma unroll
    for (int it = 0; it < 6; ++it) {
      int idx = tid + it * 256;
      int n = idx >> 3, c8 = (idx & 7) * 8;
      wreg[it] = *(const short8*)(wsrc + n * 64 + c8);
    }
  };
  auto comp_vv = [&]() {
    float sum[16];
    #pragma unroll
    for (int k = 0; k < 16; ++k) sum[k] = 0.0f;
    #pragma unroll
    for (int q = 0; q < 4; ++q) {
      #pragma unroll
      for (int k = 0; k < 8; ++k) {
        sum[k]     += wt_[q] * bf2f(u_[q][0][k]);
        sum[k + 8] += wt_[q] * bf2f(u_[q][1][k]);
      }
    }
    #pragma unroll
    for (int k = 0; k < 16; ++k) vv[k] = bf16rne(sum[k]);
  };

  __syncthreads();            // lds_f ready
  // prologue: l=0 state into regs (not hidden; happens once)
  load_w(0);
  comp_offs(0);
  load_gather();
  comp_vv();

  for (int l = 0; l < 13; ++l) {
    __syncthreads();          // A: everyone done reading LDS for l-1
    #pragma unroll
    for (int it = 0; it < 6; ++it) {
      int idx = tid + it * 256;
      int n = idx >> 3, c8 = (idx & 7) * 8;
      *(short8*)(lds_w + n * 72 + c8) = wreg[it];
    }
    *(short8*)(lds_v + pp * 72 + cg * 16)     = *(short8*)&vv[0];
    *(short8*)(lds_v + pp * 72 + cg * 16 + 8) = *(short8*)&vv[8];
    __syncthreads();          // B: LDS for l ready
    if (l < 12) {             // issue next-iter loads; latency hides under MFMA
      load_w(l + 1);
      comp_offs(l + 1);
      load_gather();
    }
    #pragma unroll
    for (int ks = 0; ks < 2; ++ks) {
      short8 af[3], bfr[4];
      #pragma unroll
      for (int i = 0; i < 3; ++i)
        af[i] = *(const short8*)(lds_w + (48 * cg + i * 16 + ml) * 72 + ks * 32 + qd * 8);
      #pragma unroll
      for (int j = 0; j < 4; ++j)
        bfr[j] = *(const short8*)(lds_v + (j * 16 + ml) * 72 + ks * 32 + qd * 8);
      #pragma unroll
      for (int i = 0; i < 3; ++i)
        #pragma unroll
        for (int j = 0; j < 4; ++j)
          acc[i][j] = __builtin_amdgcn_mfma_f32_16x16x32_bf16(af[i], bfr[j], acc[i][j], 0, 0, 0);
    }
    if (l < 12) comp_vv();    // VALU pack overlaps MFMA pipe
  }

  __syncthreads();
  #pragma unroll
  for (int i = 0; i < 3; ++i)
    #pragma unroll
    for (int j = 0; j < 4; ++j)
      #pragma unroll
      for (int r = 0; r < 4; ++r) {
        int ch = 48 * cg + i * 16 + qd * 4 + r;
        int px = j * 16 + ml;
        lds_h[ch * 65 + px] = acc[i][j][r];
      }
  __syncthreads();

  const short* i2hb = i2h + (size_t)b * 192 * HW + p;
  float* ob = outb + (size_t)b * ostr;
  float hnv[16];
  #pragma unroll
  for (int k = 0; k < 16; ++k) {
    int cch = cg + k * 4;
    float rh = lds_h[cch * 65 + pp] + wb[cch];
    float uh = lds_h[(64 + cch) * 65 + pp] + wb[64 + cch];
    float nh = lds_h[(128 + cch) * 65 + pp] + wb[128 + cch];
    float rt = bf2f(i2hb[(size_t)cch * HW]);
    float ut = bf2f(i2hb[(size_t)(64 + cch) * HW]);
    float nt = bf2f(i2hb[(size_t)(128 + cch) * HW]);
    float rr = sigmoidf_(rt + rh);
    float uu = sigmoidf_(ut + uh);
    float nn = sigmoidf_(nt + rr * nh);
    float hp = hb[(size_t)cch * HW + p];
    float hn = (1.0f - uu) * nn + uu * hp;
    ob[(size_t)cch * HW + p] = hn;
    if (lastb) lastb[((size_t)b * 64 + cch) * HW + p] = hn;
    hnv[k] = hn;
  }

  __syncthreads();
  #pragma unroll
  for (int k = 0; k < 16; ++k)
    hpack[pp * 80 + cg + 4 * k] = bf16rne(hnv[k]);
  __syncthreads();
  {
    int px = tid >> 2, g = tid & 3;
    short8 a0 = *(short8*)(hpack + px * 80 + g * 16);
    short8 a1 = *(short8*)(hpack + px * 80 + g * 16 + 8);
    short* dst = hbf_out + ((size_t)b * HW + tile * 64 + px) * 64 + g * 16;
    *(short8*)dst = a0;
    *(short8*)(dst + 8) = a1;
  }
}

// ---------------------------------------------------------------------------
extern "C" void kernel_launch(void* const* d_in, const int* in_sizes, int n_in,
                              void* d_out, int out_size, void* d_ws, size_t ws_size,
                              hipStream_t stream)
{
  const float* inp   = (const float*)d_in[0];
  const float* state = (const float*)d_in[1];
  const float* i2h_w = (const float*)d_in[2];
  const float* i2h_b = (const float*)d_in[3];
  const float* i2f_w = (const float*)d_in[4];
  const float* i2f_b = (const float*)d_in[5];
  const float* h2f_w = (const float*)d_in[6];
  const float* h2f_b = (const float*)d_in[7];
  const float* fl_w  = (const float*)d_in[8];
  const float* fl_b  = (const float*)d_in[9];
  const float* wr_w  = (const float*)d_in[10];
  const float* wr_b  = (const float*)d_in[11];
  float* out = (float*)d_out;
  float* ws  = (float*)d_ws;

  // sizes in floats
  const long long F_I2HB1 = 3538944;   // one step: 4*192*HW shorts /2
  const long long F_FBF   = 589824;    // 4*HW*32 shorts /2
  const long long F_FLS   = 958464;    // 4*26*HW fp32
  const long long F_HB    = 1179648;   // 4*HW*64 shorts /2
  const long long F_XBF   = 1474560;   // 40*HW*8 shorts /2
  const long long F_WBF   = 79872;
  const long long F_WHK   = 25600;
  const long long F_WIK   = 3584;
  const long long F_FLK   = 12800;
  const long long F_I2HK  = 9216;      // 3*192*32 shorts /2
  const long long OB      = (long long)10 * 64 * HW;

  const long long fixed = F_FBF + F_FLS + 2 * F_HB + F_XBF + F_WBF
                        + F_WHK + F_WIK + F_FLK + F_I2HK;
  bool batched = ws_size >= (size_t)(10 * F_I2HB1 + fixed) * 4ULL;
  long long i2h_fl = batched ? 10 * F_I2HB1 : F_I2HB1;

  short* ws_i2h = (short*)ws;
  float* fwp    = ws + i2h_fl;
  float* ws_fbf_f = fwp;              fwp += F_FBF;
  float* ws_fls   = fwp;              fwp += F_FLS;
  float* hbfA_f   = fwp;              fwp += F_HB;
  float* hbfB_f   = fwp;              fwp += F_HB;
  float* xbf_f    = fwp;              fwp += F_XBF;
  float* wbf_f    = fwp;              fwp += F_WBF;
  float* whK_f    = fwp;              fwp += F_WHK;
  float* wiK_f    = fwp;              fwp += F_WIK;
  float* flK_f    = fwp;              fwp += F_FLK;
  float* i2hK_f   = fwp;
  short* ws_fbf  = (short*)ws_fbf_f;
  short* hbfA    = (short*)hbfA_f;
  short* hbfB    = (short*)hbfB_f;
  short* ws_xbf  = (short*)xbf_f;
  short* ws_wbf  = (short*)wbf_f;
  short* ws_whK  = (short*)whK_f;
  short* ws_wiK  = (short*)wiK_f;
  short* ws_flK  = (short*)flK_f;
  short* ws_i2hK = (short*)i2hK_f;

  k_wconv<<<dim3(624), 256, 0, stream>>>(wr_w, ws_wbf);
  k_pack<<<dim3(400), 256, 0, stream>>>(h2f_w, i2f_w, fl_w, i2h_w,
                                        ws_whK, ws_wiK, ws_flK, ws_i2hK);
  k_h2bf<<<dim3(144, 4), 256, 0, stream>>>(state, hbfA);
  k_x2bf<<<dim3(36, 40), 256, 0, stream>>>(inp, ws_xbf);
  if (batched)
    k_i2h<<<dim3(72, 40), 256, 0, stream>>>(ws_xbf, 0, ws_i2hK, i2h_b, ws_i2h);

  for (int t = 0; t < 10; ++t) {
    const float* hbase = (t == 0) ? state : (out + (size_t)(t - 1) * 64 * HW);
    long long hstr = (t == 0) ? (long long)64 * HW : OB;
    short* hin  = (t & 1) ? hbfB : hbfA;
    short* hout = (t & 1) ? hbfA : hbfB;

    if (!batched)
      k_i2h<<<dim3(72, 4), 256, 0, stream>>>(ws_xbf, t, ws_i2hK, i2h_b, ws_i2h);
    k_f<<<dim3(144, 4), 256, 0, stream>>>(ws_xbf, t, hin, ws_whK, ws_wiK,
                                          i2f_b, h2f_b, ws_fbf);
    k_flows<<<dim3(144, 4), 256, 0, stream>>>(ws_fbf, ws_flK, fl_b, ws_fls);

    const short* i2h_t = batched ? (ws_i2h + (size_t)t * 2 * F_I2HB1) : ws_i2h;
    float* outbase = out + (size_t)t * 64 * HW;
    float* lastb = (t == 9) ? (out + (size_t)4 * 10 * 64 * HW) : nullptr;
    k_fused<<<dim3(576), 256, 0, stream>>>(ws_fls, hbase, hstr, hin, i2h_t,
                                           ws_wbf, wr_b, outbase, OB, hout, lastb);
  }
}